// Round 1
// baseline (239.770 us; speedup 1.0000x reference)
//
#include <hip/hip_runtime.h>
#include <math.h>

// CopyMamba3LM, token-id factorization (round 3).
// R1 lesson: per-lane row-walk dot products (lane i reads w[i*512+d]) touch
// 64 cache lines per wave-load -> ktok_pre dominated at ~100 us. Fix: pack
// transposed, d-major operands once (coalesced dwordx4 across lanes).
// R3 (this round): bench infra failed last round (no counters). Safe tweaks
// only: (1) ktok q/k + vocab dot loops fused (one pass over hs, 2 load
// streams in flight -- latency-bound kernel at 1 wave/SIMD), (2) kwrite token
// loads hoisted above the erow barrier, (3) nt store for out_logmix,
// (4) int4 histogram reads. Output kernel is write-bound: ~151 MB stores
// ~= 24-38 us floor depending on store-only ceiling.

#define DM 512
#define VC 256
#define SL 2048
#define NB 8
#define AD 64

typedef float f4v __attribute__((ext_vector_type(4)));

__device__ __forceinline__ float wave_sum(float v) {
#pragma unroll
  for (int o = 32; o > 0; o >>= 1) v += __shfl_xor(v, o, 64);
  return v;
}
__device__ __forceinline__ float wave_max(float v) {
#pragma unroll
  for (int o = 32; o > 0; o >>= 1) v = fmaxf(v, __shfl_xor(v, o, 64));
  return v;
}
// block = 256 threads = 4 waves
__device__ __forceinline__ float blk_sum(float v, float* red) {
  v = wave_sum(v);
  if ((threadIdx.x & 63) == 0) red[threadIdx.x >> 6] = v;
  __syncthreads();
  float r = red[0] + red[1] + red[2] + red[3];
  __syncthreads();
  return r;
}
__device__ __forceinline__ float blk_max(float v, float* red) {
  v = wave_max(v);
  if ((threadIdx.x & 63) == 0) red[threadIdx.x >> 6] = v;
  __syncthreads();
  float r = fmaxf(fmaxf(red[0], red[1]), fmaxf(red[2], red[3]));
  __syncthreads();
  return r;
}

// K1: pack transposed operands + per-batch token histogram.
// blocks 0..511: d = blockIdx -> embed_P[((d/4)*256+v)*4 + d%4] etc.
// blocks 512..519: histogram for batch blockIdx-512.
__global__ __launch_bounds__(256) void kprep(
    const float* __restrict__ embed_w, const float* __restrict__ q_w,
    const float* __restrict__ k_w, const int* __restrict__ tokens,
    const int* __restrict__ prefix_lens,
    float* __restrict__ embed_P, float* __restrict__ qk_P,
    int* __restrict__ cnt)
{
  __shared__ int c[VC];
  const int blk = blockIdx.x;
  const int tid = threadIdx.x;
  if (blk < DM) {
    const int d = blk;
    embed_P[(((d >> 2) * VC + tid) << 2) + (d & 3)] = embed_w[tid * DM + d];
    if (tid < 128) {
      float val = (tid < 64) ? q_w[tid * DM + d] : k_w[(tid - 64) * DM + d];
      qk_P[(((d >> 2) * 128 + tid) << 2) + (d & 3)] = val;
    }
  } else {
    const int b = blk - DM;
    c[tid] = 0;
    __syncthreads();
    const int P = prefix_lens[b];
    const int4* trow = (const int4*)(tokens + b * SL);
#pragma unroll
    for (int i = tid; i < SL / 4; i += 256) {
      int4 tk = trow[i];
      int s0 = i * 4;
      if (s0     < P && tk.x != 0) atomicAdd(&c[tk.x], 1);
      if (s0 + 1 < P && tk.y != 0) atomicAdd(&c[tk.y], 1);
      if (s0 + 2 < P && tk.z != 0) atomicAdd(&c[tk.z], 1);
      if (s0 + 3 < P && tk.w != 0) atomicAdd(&c[tk.w], 1);
    }
    __syncthreads();
    cnt[b * VC + tid] = c[tid];
  }
}

// K2: per-token h = LN(LN(embed[tt])), gate, q row, k row (written transposed
// packed), vocab logits + softmax. All inner loads coalesced dwordx4.
// q/k dot and vocab dot share ONE pass over hs (two load streams in flight;
// tid<128 branch is wave-uniform).
__global__ __launch_bounds__(256) void ktok(
    const float* __restrict__ embed_w,
    const float* __restrict__ en_g, const float* __restrict__ en_b,
    const float* __restrict__ fn_g, const float* __restrict__ fn_b,
    const float* __restrict__ q_b, const float* __restrict__ k_b,
    const float* __restrict__ g_w, const float* __restrict__ g_b,
    const float* __restrict__ embed_P, const float* __restrict__ qk_P,
    float* __restrict__ q_tok, float* __restrict__ kT_P,
    float* __restrict__ gate_tok, float* __restrict__ probs_tok)
{
  __shared__ float red[4];
  __shared__ __align__(16) float hs[DM];
  const int tt = blockIdx.x;    // token id
  const int tid = threadIdx.x;  // owns dims tid, tid+256

  float x0 = embed_w[tt * DM + tid];
  float x1 = embed_w[tt * DM + 256 + tid];
  // LN 1 (embed_norm)
  float mu = blk_sum(x0 + x1, red) * (1.0f / DM);
  float d0 = x0 - mu, d1 = x1 - mu;
  float var = blk_sum(d0 * d0 + d1 * d1, red) * (1.0f / DM);
  float inv = 1.0f / sqrtf(var + 1e-5f);
  float y0 = d0 * inv * en_g[tid] + en_b[tid];
  float y1 = d1 * inv * en_g[tid + 256] + en_b[tid + 256];
  // LN 2 (final_norm)
  mu = blk_sum(y0 + y1, red) * (1.0f / DM);
  d0 = y0 - mu; d1 = y1 - mu;
  var = blk_sum(d0 * d0 + d1 * d1, red) * (1.0f / DM);
  inv = 1.0f / sqrtf(var + 1e-5f);
  float h0 = d0 * inv * fn_g[tid] + fn_b[tid];
  float h1 = d1 * inv * fn_g[tid + 256] + fn_b[tid + 256];
  hs[tid] = h0; hs[tid + 256] = h1;
  // gate (blk_sum's barrier also publishes hs[])
  float gp = blk_sum(h0 * g_w[tid] + h1 * g_w[tid + 256], red);
  if (tid == 0) gate_tok[tt] = 1.0f / (1.0f + expf(-(gp + g_b[0])));

  const float4* hs4 = (const float4*)hs;
  const float4* w4p = (const float4*)qk_P;
  const float4* e4p = (const float4*)embed_P;
  const bool qk_lane = (tid < 128);  // wave-uniform (waves 0,1)
  float acc = 0.0f;  // q/k dot (threads 0..127)
  float lt = 0.0f;   // vocab logit (thread tid = vocab v)
#pragma unroll 8
  for (int d4 = 0; d4 < DM / 4; ++d4) {
    float4 h4 = hs4[d4];
    float4 e4 = e4p[d4 * VC + tid];
    lt += h4.x * e4.x + h4.y * e4.y + h4.z * e4.z + h4.w * e4.w;
    if (qk_lane) {
      float4 w4 = w4p[d4 * 128 + tid];
      acc += h4.x * w4.x + h4.y * w4.y + h4.z * w4.z + h4.w * w4.w;
    }
  }
  if (qk_lane) {
    if (tid < 64) {
      q_tok[tt * AD + tid] = acc + q_b[tid];
    } else {
      int a = tid - 64;
      kT_P[(((a >> 2) * VC + tt) << 2) + (a & 3)] = acc + k_b[a];
    }
  }
  // tied vocab head softmax
  float m = blk_max(lt, red);
  float e = expf(lt - m);
  float Z = blk_sum(e, red);
  probs_tok[tt * VC + tid] = e / Z;
}

// K3: per (b, token-id) masked softmax tables (scores recomputed coalesced
// from packed k^T): e_norm[b][tt][v], logmix[b][tt][v].
__global__ __launch_bounds__(256) void ktables(
    const float* __restrict__ q_tok, const float* __restrict__ kT_P,
    const int* __restrict__ cnt, const float* __restrict__ gate_tok,
    const float* __restrict__ probs_tok,
    float* __restrict__ e_norm, float* __restrict__ logmix)
{
  __shared__ float red[4];
  __shared__ __align__(16) float qs[AD];
  const int b = blockIdx.x >> 8, tt = blockIdx.x & 255;
  const int v = threadIdx.x;
  if (v < AD) qs[v] = q_tok[tt * AD + v];
  __syncthreads();
  const float4* qs4 = (const float4*)qs;
  const float4* k4p = (const float4*)kT_P;
  float sv = 0.0f;
#pragma unroll
  for (int a4 = 0; a4 < AD / 4; ++a4) {
    float4 q4 = qs4[a4];
    float4 k4 = k4p[a4 * VC + v];
    sv += q4.x * k4.x + q4.y * k4.y + q4.z * k4.z + q4.w * k4.w;
  }
  sv *= 0.125f;  // 1/sqrt(64)
  int c = cnt[b * VC + v];
  float m = blk_max(c > 0 ? sv : -1e30f, red);  // max over unmasked keys
  float e = expf(sv - m);
  float Z = blk_sum((float)c * e, red);
  float en = e / Z;
  int idx = (b * VC + tt) * VC + v;
  e_norm[idx] = en;
  float g = gate_tok[tt];
  float mixed = g * probs_tok[tt * VC + v] + (1.0f - g) * ((float)c * en);
  logmix[idx] = logf(fmaxf(mixed, 1e-12f));
}

// K4: output writer — one block per (b,t) row; ~151 MB of stores.
// Token int4 loads issued BEFORE the erow staging chain + barrier so their
// L2 latency overlaps it.
__global__ __launch_bounds__(256) void kwrite(
    const int* __restrict__ tokens, const int* __restrict__ prefix_lens,
    const float* __restrict__ e_norm, const float* __restrict__ logmix,
    const float* __restrict__ gate_tok,
    float* __restrict__ out_logmix, float* __restrict__ out_gate,
    float* __restrict__ out_attn)
{
  __shared__ float erow[VC];
  const int row = blockIdx.x;  // b*SL + t
  const int b = row >> 11;
  const int tid = threadIdx.x;
  const int P = prefix_lens[b];
  const int4* tokrow = (const int4*)(tokens + b * SL);
  // issue early: independent of the tokens[row]->e_norm dependent chain
  int4 tk0 = tokrow[tid];
  int4 tk1 = tokrow[tid + 256];
  const int tt = tokens[row];
  const int base = (b * VC + tt) * VC;
  erow[tid] = e_norm[base + tid];
  __builtin_nontemporal_store(logmix[base + tid],
                              &out_logmix[(size_t)row * VC + tid]);
  if (tid == 0) out_gate[row] = gate_tok[tt];
  __syncthreads();
  f4v* arow = (f4v*)(out_attn + (size_t)row * SL);
  {
    int s0 = tid * 4;
    f4v val;
    val.x = (s0     < P && tk0.x != 0) ? erow[tk0.x] : 0.0f;
    val.y = (s0 + 1 < P && tk0.y != 0) ? erow[tk0.y] : 0.0f;
    val.z = (s0 + 2 < P && tk0.z != 0) ? erow[tk0.z] : 0.0f;
    val.w = (s0 + 3 < P && tk0.w != 0) ? erow[tk0.w] : 0.0f;
    __builtin_nontemporal_store(val, &arow[tid]);
  }
  {
    int s0 = (tid + 256) * 4;
    f4v val;
    val.x = (s0     < P && tk1.x != 0) ? erow[tk1.x] : 0.0f;
    val.y = (s0 + 1 < P && tk1.y != 0) ? erow[tk1.y] : 0.0f;
    val.z = (s0 + 2 < P && tk1.z != 0) ? erow[tk1.z] : 0.0f;
    val.w = (s0 + 3 < P && tk1.w != 0) ? erow[tk1.w] : 0.0f;
    __builtin_nontemporal_store(val, &arow[tid + 256]);
  }
}

extern "C" void kernel_launch(void* const* d_in, const int* in_sizes, int n_in,
                              void* d_out, int out_size, void* d_ws, size_t ws_size,
                              hipStream_t stream)
{
  const int*   tokens      = (const int*)  d_in[0];
  const int*   prefix_lens = (const int*)  d_in[1];
  const float* embed_w     = (const float*)d_in[2];
  const float* en_g        = (const float*)d_in[3];
  const float* en_b        = (const float*)d_in[4];
  const float* fn_g        = (const float*)d_in[5];
  const float* fn_b        = (const float*)d_in[6];
  const float* q_b         = (const float*)d_in[8];
  const float* k_b         = (const float*)d_in[10];
  const float* q_w         = (const float*)d_in[7];
  const float* k_w         = (const float*)d_in[9];
  const float* g_w         = (const float*)d_in[11];
  const float* g_b         = (const float*)d_in[12];

  // workspace layout (floats), all 16B-aligned offsets; ~5.4 MB total
  float* ws        = (float*)d_ws;
  float* embed_P   = ws;                        // 512*256 packed transpose
  float* qk_P      = embed_P + DM * VC;         // 512*128
  float* kT_P      = qk_P + DM * 128;           // 64*256
  float* q_tok     = kT_P + AD * VC;            // 256*64
  float* gate_tok  = q_tok + VC * AD;           // 256
  float* probs_tok = gate_tok + VC;             // 256*256
  int*   cnt       = (int*)(probs_tok + VC * VC);  // 8*256
  float* e_norm    = (float*)(cnt + NB * VC);   // 8*256*256
  float* logmix    = e_norm + NB * VC * VC;     // 8*256*256

  float* out_logmix = (float*)d_out;                      // 8*2048*256
  float* out_gate   = out_logmix + (size_t)NB * SL * VC;  // 8*2048
  float* out_attn   = out_gate + (size_t)NB * SL;         // 8*2048*2048

  kprep<<<DM + NB, 256, 0, stream>>>(embed_w, q_w, k_w, tokens, prefix_lens,
                                     embed_P, qk_P, cnt);
  ktok<<<VC, 256, 0, stream>>>(embed_w, en_g, en_b, fn_g, fn_b, q_b, k_b,
                               g_w, g_b, embed_P, qk_P,
                               q_tok, kT_P, gate_tok, probs_tok);
  ktables<<<NB * VC, 256, 0, stream>>>(q_tok, kT_P, cnt, gate_tok, probs_tok,
                                       e_norm, logmix);
  kwrite<<<NB * SL, 256, 0, stream>>>(tokens, prefix_lens, e_norm, logmix,
                                      gate_tok, out_logmix, out_gate, out_attn);
}

// Round 2
// 237.233 us; speedup vs baseline: 1.0107x; 1.0107x over previous
//
#include <hip/hip_runtime.h>
#include <math.h>

// CopyMamba3LM, token-id factorization (round 4).
// R1 lesson: per-lane row-walk dots touch 64 lines/wave-load -> pack
// transposed d-major operands once (coalesced dwordx4).
// R4 (this round): rocprof top-5 = harness poison fills (604 MB @6.2 TB/s,
// ~97 us each); our kernels each <96 us. Budget: 239.8 - 2x97 ~= 46 us of
// kernel time (matches sum-of-parts model). Structural fix: INVERT the
// writer. All output rows sharing (b,tt) are bitwise identical, so one
// block per (b,tt) computes the table ONCE, builds its attn slice in
// REGISTERS, and streams it to every row t with tokens[b][t]==tt
// (position lists built in kprep via scan+scatter). Removes: kernel #3,
// e_norm/logmix 4 MB round-trip, 134->17 MB token-row L2 reads, per-row
// LDS gathers. Store loop = pure reg->HBM streaming (151 MB ~= 25 us floor).
// Next-round decision tree: dur unchanged => poison floor confirmed,
// kernels near-minimal; dur -20+ => keep squeezing kfused.

#define DM 512
#define VC 256
#define SL 2048
#define NB 8
#define AD 64

typedef float f4v __attribute__((ext_vector_type(4)));

__device__ __forceinline__ float wave_sum(float v) {
#pragma unroll
  for (int o = 32; o > 0; o >>= 1) v += __shfl_xor(v, o, 64);
  return v;
}
__device__ __forceinline__ float wave_max(float v) {
#pragma unroll
  for (int o = 32; o > 0; o >>= 1) v = fmaxf(v, __shfl_xor(v, o, 64));
  return v;
}
// block = 256 threads = 4 waves
__device__ __forceinline__ float blk_sum(float v, float* red) {
  v = wave_sum(v);
  if ((threadIdx.x & 63) == 0) red[threadIdx.x >> 6] = v;
  __syncthreads();
  float r = red[0] + red[1] + red[2] + red[3];
  __syncthreads();
  return r;
}
__device__ __forceinline__ float blk_max(float v, float* red) {
  v = wave_max(v);
  if ((threadIdx.x & 63) == 0) red[threadIdx.x >> 6] = v;
  __syncthreads();
  float r = fmaxf(fmaxf(red[0], red[1]), fmaxf(red[2], red[3]));
  __syncthreads();
  return r;
}

// K1: pack transposed operands + per-batch token histogram/scan/position-lists.
// blocks 0..511: d = blockIdx -> embed_P / qk_P packing.
// blocks 512..519: batch b = blockIdx-512: masked cnt, full counts ncnt,
//                  exclusive offsets offs, position list (scatter).
__global__ __launch_bounds__(256) void kprep(
    const float* __restrict__ embed_w, const float* __restrict__ q_w,
    const float* __restrict__ k_w, const int* __restrict__ tokens,
    const int* __restrict__ prefix_lens,
    float* __restrict__ embed_P, float* __restrict__ qk_P,
    int* __restrict__ cnt, int* __restrict__ ncnt,
    int* __restrict__ offs, int* __restrict__ list)
{
  __shared__ int c[VC];    // masked (s < P) counts
  __shared__ int ca[VC];   // all-position counts
  __shared__ int off[VC];  // scan workspace -> exclusive offsets
  __shared__ int cur[VC];  // scatter cursors
  const int blk = blockIdx.x;
  const int tid = threadIdx.x;
  if (blk < DM) {
    const int d = blk;
    embed_P[(((d >> 2) * VC + tid) << 2) + (d & 3)] = embed_w[tid * DM + d];
    if (tid < 128) {
      float val = (tid < 64) ? q_w[tid * DM + d] : k_w[(tid - 64) * DM + d];
      qk_P[(((d >> 2) * 128 + tid) << 2) + (d & 3)] = val;
    }
  } else {
    const int b = blk - DM;
    c[tid] = 0; ca[tid] = 0;
    __syncthreads();
    const int P = prefix_lens[b];
    const int4* trow = (const int4*)(tokens + b * SL);
#pragma unroll
    for (int i = tid; i < SL / 4; i += 256) {
      int4 tk = trow[i];
      int s0 = i * 4;
      atomicAdd(&ca[tk.x], 1); atomicAdd(&ca[tk.y], 1);
      atomicAdd(&ca[tk.z], 1); atomicAdd(&ca[tk.w], 1);
      if (s0     < P && tk.x != 0) atomicAdd(&c[tk.x], 1);
      if (s0 + 1 < P && tk.y != 0) atomicAdd(&c[tk.y], 1);
      if (s0 + 2 < P && tk.z != 0) atomicAdd(&c[tk.z], 1);
      if (s0 + 3 < P && tk.w != 0) atomicAdd(&c[tk.w], 1);
    }
    __syncthreads();
    // inclusive Hillis-Steele scan of ca -> off, then exclusive
    int myc = ca[tid];
    off[tid] = myc;
    __syncthreads();
    for (int d2 = 1; d2 < VC; d2 <<= 1) {
      int add = (tid >= d2) ? off[tid - d2] : 0;
      __syncthreads();
      off[tid] += add;
      __syncthreads();
    }
    int excl = off[tid] - myc;
    cur[tid] = excl;
    __syncthreads();
    // scatter positions grouped by token value (order within group arbitrary;
    // every row written exactly once downstream, content identical per group)
#pragma unroll
    for (int i = tid; i < SL / 4; i += 256) {
      int4 tk = trow[i];
      int s0 = i * 4;
      int p;
      p = atomicAdd(&cur[tk.x], 1); list[b * SL + p] = s0;
      p = atomicAdd(&cur[tk.y], 1); list[b * SL + p] = s0 + 1;
      p = atomicAdd(&cur[tk.z], 1); list[b * SL + p] = s0 + 2;
      p = atomicAdd(&cur[tk.w], 1); list[b * SL + p] = s0 + 3;
    }
    __syncthreads();
    cnt [b * VC + tid] = c[tid];
    ncnt[b * VC + tid] = myc;
    offs[b * VC + tid] = excl;
  }
}

// K2: per-token h = LN(LN(embed[tt])), gate, q row, k row (transposed packed),
// vocab logits + softmax. q/k dot and vocab dot share one pass over hs.
__global__ __launch_bounds__(256) void ktok(
    const float* __restrict__ embed_w,
    const float* __restrict__ en_g, const float* __restrict__ en_b,
    const float* __restrict__ fn_g, const float* __restrict__ fn_b,
    const float* __restrict__ q_b, const float* __restrict__ k_b,
    const float* __restrict__ g_w, const float* __restrict__ g_b,
    const float* __restrict__ embed_P, const float* __restrict__ qk_P,
    float* __restrict__ q_tok, float* __restrict__ kT_P,
    float* __restrict__ gate_tok, float* __restrict__ probs_tok)
{
  __shared__ float red[4];
  __shared__ __align__(16) float hs[DM];
  const int tt = blockIdx.x;    // token id
  const int tid = threadIdx.x;  // owns dims tid, tid+256

  float x0 = embed_w[tt * DM + tid];
  float x1 = embed_w[tt * DM + 256 + tid];
  // LN 1 (embed_norm)
  float mu = blk_sum(x0 + x1, red) * (1.0f / DM);
  float d0 = x0 - mu, d1 = x1 - mu;
  float var = blk_sum(d0 * d0 + d1 * d1, red) * (1.0f / DM);
  float inv = 1.0f / sqrtf(var + 1e-5f);
  float y0 = d0 * inv * en_g[tid] + en_b[tid];
  float y1 = d1 * inv * en_g[tid + 256] + en_b[tid + 256];
  // LN 2 (final_norm)
  mu = blk_sum(y0 + y1, red) * (1.0f / DM);
  d0 = y0 - mu; d1 = y1 - mu;
  var = blk_sum(d0 * d0 + d1 * d1, red) * (1.0f / DM);
  inv = 1.0f / sqrtf(var + 1e-5f);
  float h0 = d0 * inv * fn_g[tid] + fn_b[tid];
  float h1 = d1 * inv * fn_g[tid + 256] + fn_b[tid + 256];
  hs[tid] = h0; hs[tid + 256] = h1;
  // gate (blk_sum's barrier also publishes hs[])
  float gp = blk_sum(h0 * g_w[tid] + h1 * g_w[tid + 256], red);
  if (tid == 0) gate_tok[tt] = 1.0f / (1.0f + expf(-(gp + g_b[0])));

  const float4* hs4 = (const float4*)hs;
  const float4* w4p = (const float4*)qk_P;
  const float4* e4p = (const float4*)embed_P;
  const bool qk_lane = (tid < 128);  // wave-uniform (waves 0,1)
  float acc = 0.0f;  // q/k dot (threads 0..127)
  float lt = 0.0f;   // vocab logit (thread tid = vocab v)
#pragma unroll 8
  for (int d4 = 0; d4 < DM / 4; ++d4) {
    float4 h4 = hs4[d4];
    float4 e4 = e4p[d4 * VC + tid];
    lt += h4.x * e4.x + h4.y * e4.y + h4.z * e4.z + h4.w * e4.w;
    if (qk_lane) {
      float4 w4 = w4p[d4 * 128 + tid];
      acc += h4.x * w4.x + h4.y * w4.y + h4.z * w4.z + h4.w * w4.w;
    }
  }
  if (qk_lane) {
    if (tid < 64) {
      q_tok[tt * AD + tid] = acc + q_b[tid];
    } else {
      int a = tid - 64;
      kT_P[(((a >> 2) * VC + tt) << 2) + (a & 3)] = acc + k_b[a];
    }
  }
  // tied vocab head softmax
  float m = blk_max(lt, red);
  float e = expf(lt - m);
  float Z = blk_sum(e, red);
  probs_tok[tt * VC + tid] = e / Z;
}

// K3 (fused ktables+kwrite, inverted): one block per (b,tt). Compute the
// masked-softmax table row once (bitwise-identical math to old ktables),
// build this thread's attn slice in REGISTERS (one gather per block, not
// per row), then stream the identical row to every position t with
// tokens[b][t]==tt. ~151 MB of pure streaming NT stores.
__global__ __launch_bounds__(256) void kfused(
    const float* __restrict__ q_tok, const float* __restrict__ kT_P,
    const int* __restrict__ cnt, const int* __restrict__ ncnt,
    const int* __restrict__ offs, const int* __restrict__ list,
    const float* __restrict__ gate_tok, const float* __restrict__ probs_tok,
    const int* __restrict__ tokens, const int* __restrict__ prefix_lens,
    float* __restrict__ out_logmix, float* __restrict__ out_gate,
    float* __restrict__ out_attn)
{
  __shared__ float red[4];
  __shared__ __align__(16) float qs[AD];
  __shared__ __align__(16) float erow[VC];
  const int b = blockIdx.x >> 8, tt = blockIdx.x & 255;
  const int tid = threadIdx.x;  // = vocab v for the table phase

  // hoist independent loads (hide L2 latency under the dot/reductions)
  const int P = prefix_lens[b];
  const int4* tokrow = (const int4*)(tokens + b * SL);
  int4 tk0 = tokrow[tid];
  int4 tk1 = tokrow[tid + 256];
  const int nr = ncnt[b * VC + tt];
  const int base_off = offs[b * VC + tt];
  const float pv = probs_tok[tt * VC + tid];
  const float g = gate_tok[tt];
  if (tid < AD) qs[tid] = q_tok[tt * AD + tid];
  __syncthreads();

  const float4* qs4 = (const float4*)qs;
  const float4* k4p = (const float4*)kT_P;
  float sv = 0.0f;
#pragma unroll
  for (int a4 = 0; a4 < AD / 4; ++a4) {
    float4 q4 = qs4[a4];
    float4 k4 = k4p[a4 * VC + tid];
    sv += q4.x * k4.x + q4.y * k4.y + q4.z * k4.z + q4.w * k4.w;
  }
  sv *= 0.125f;  // 1/sqrt(64)
  int c = cnt[b * VC + tid];
  float m = blk_max(c > 0 ? sv : -1e30f, red);  // max over unmasked keys
  float e = expf(sv - m);
  float Z = blk_sum((float)c * e, red);
  float en = e / Z;
  erow[tid] = en;
  float lv = logf(fmaxf(g * pv + (1.0f - g) * ((float)c * en), 1e-12f));
  __syncthreads();  // publish erow

  // build this thread's attn slice once, in registers
  f4v a0, a1;
  {
    int s0 = tid * 4;
    a0.x = (s0     < P && tk0.x != 0) ? erow[tk0.x] : 0.0f;
    a0.y = (s0 + 1 < P && tk0.y != 0) ? erow[tk0.y] : 0.0f;
    a0.z = (s0 + 2 < P && tk0.z != 0) ? erow[tk0.z] : 0.0f;
    a0.w = (s0 + 3 < P && tk0.w != 0) ? erow[tk0.w] : 0.0f;
  }
  {
    int s0 = (tid + 256) * 4;
    a1.x = (s0     < P && tk1.x != 0) ? erow[tk1.x] : 0.0f;
    a1.y = (s0 + 1 < P && tk1.y != 0) ? erow[tk1.y] : 0.0f;
    a1.z = (s0 + 2 < P && tk1.z != 0) ? erow[tk1.z] : 0.0f;
    a1.w = (s0 + 3 < P && tk1.w != 0) ? erow[tk1.w] : 0.0f;
  }

  // stream the identical row to every matching position
  const int* lp = list + b * SL + base_off;
  for (int r = 0; r < nr; ++r) {
    int t = lp[r];
    size_t row = (size_t)(b * SL + t);
    __builtin_nontemporal_store(lv, &out_logmix[row * VC + tid]);
    if (tid == 0) out_gate[row] = g;
    f4v* ar = (f4v*)(out_attn + row * SL);
    __builtin_nontemporal_store(a0, &ar[tid]);
    __builtin_nontemporal_store(a1, &ar[tid + 256]);
  }
}

extern "C" void kernel_launch(void* const* d_in, const int* in_sizes, int n_in,
                              void* d_out, int out_size, void* d_ws, size_t ws_size,
                              hipStream_t stream)
{
  const int*   tokens      = (const int*)  d_in[0];
  const int*   prefix_lens = (const int*)  d_in[1];
  const float* embed_w     = (const float*)d_in[2];
  const float* en_g        = (const float*)d_in[3];
  const float* en_b        = (const float*)d_in[4];
  const float* fn_g        = (const float*)d_in[5];
  const float* fn_b        = (const float*)d_in[6];
  const float* q_b         = (const float*)d_in[8];
  const float* k_b         = (const float*)d_in[10];
  const float* q_w         = (const float*)d_in[7];
  const float* k_w         = (const float*)d_in[9];
  const float* g_w         = (const float*)d_in[11];
  const float* g_b         = (const float*)d_in[12];

  // workspace layout (floats), all 16B-aligned offsets; ~1.3 MB total
  float* ws        = (float*)d_ws;
  float* embed_P   = ws;                        // 512*256 packed transpose
  float* qk_P      = embed_P + DM * VC;         // 512*128
  float* kT_P      = qk_P + DM * 128;           // 64*256
  float* q_tok     = kT_P + AD * VC;            // 256*64
  float* gate_tok  = q_tok + VC * AD;           // 256
  float* probs_tok = gate_tok + VC;             // 256*256
  int*   cnt       = (int*)(probs_tok + VC * VC);  // 8*256 masked counts
  int*   ncnt      = cnt + NB * VC;             // 8*256 full counts
  int*   offs      = ncnt + NB * VC;            // 8*256 exclusive offsets
  int*   list      = offs + NB * VC;            // 8*2048 position lists

  float* out_logmix = (float*)d_out;                      // 8*2048*256
  float* out_gate   = out_logmix + (size_t)NB * SL * VC;  // 8*2048
  float* out_attn   = out_gate + (size_t)NB * SL;         // 8*2048*2048

  kprep<<<DM + NB, 256, 0, stream>>>(embed_w, q_w, k_w, tokens, prefix_lens,
                                     embed_P, qk_P, cnt, ncnt, offs, list);
  ktok<<<VC, 256, 0, stream>>>(embed_w, en_g, en_b, fn_g, fn_b, q_b, k_b,
                               g_w, g_b, embed_P, qk_P,
                               q_tok, kT_P, gate_tok, probs_tok);
  kfused<<<NB * VC, 256, 0, stream>>>(q_tok, kT_P, cnt, ncnt, offs, list,
                                      gate_tok, probs_tok, tokens, prefix_lens,
                                      out_logmix, out_gate, out_attn);
}